// Round 2
// baseline (821.123 us; speedup 1.0000x reference)
//
#include <hip/hip_runtime.h>

// Fully fused: grouped conv3x3x3 (q from x; k,v from last) -> 5x5 attention over
// depth per (batch, head, y, x) -> grouped 1x1x1 proj.
//
// Key structure (R2): all global loads are buffer_load with per-ROW SRDs.
//  - blockDim = 64 (one wave) so py = f(blockIdx) is wave-uniform -> SRDs are
//    built entirely on the scalar pipe (s_add), zero VALU per load.
//  - num_records = 512 bytes (one image row). Out-of-row accesses (x halo at
//    px==0/127 via voffset, y halo via num_records=0) return hardware 0 --
//    exactly the conv zero-padding. No cndmask, no branches.
//  - stores: raw.buffer.store with scalar soffset -> VALU-free epilogue.
//  - block-id swizzle gives each XCD contiguous (z,y) slabs for L2 halo reuse.

#define WD    128
#define HWn   (128 * 128)
#define BD    5
#define CS    (BD * HWn)          // channel stride (elements) = 81920
#define CFGW  0x00020000u         // SRD word3: raw untyped dword

typedef int v4i __attribute__((ext_vector_type(4)));

__device__ float amd_buf_load_f32(v4i rsrc, int voffset, int soffset, int aux)
    __asm("llvm.amdgcn.raw.buffer.load.f32");
__device__ void amd_buf_store_f32(float data, v4i rsrc, int voffset, int soffset, int aux)
    __asm("llvm.amdgcn.raw.buffer.store.f32");

union SRD {
    v4i v;
    struct { const void* base; unsigned nr; unsigned cfg; } s;
};
static_assert(sizeof(SRD) == 16, "SRD must be 16 bytes");

// Load the 3x3 spatial taps of one (channel, depth) plane. rb points at row
// (py-1) of the plane (may be 512B before the plane; guarded by nr_t=0).
__device__ __forceinline__ void load9(const char* rb, unsigned nr_t, unsigned nr_b,
                                      int vl, int vcn, int vr, float t[9])
{
    SRD r0, r1, r2;
    r0.s.base = rb;        r0.s.nr = nr_t; r0.s.cfg = CFGW;
    r1.s.base = rb + 512;  r1.s.nr = 512u; r1.s.cfg = CFGW;
    r2.s.base = rb + 1024; r2.s.nr = nr_b; r2.s.cfg = CFGW;
    t[0] = amd_buf_load_f32(r0.v, vl,  0, 0);
    t[1] = amd_buf_load_f32(r0.v, vcn, 0, 0);
    t[2] = amd_buf_load_f32(r0.v, vr,  0, 0);
    t[3] = amd_buf_load_f32(r1.v, vl,  0, 0);
    t[4] = amd_buf_load_f32(r1.v, vcn, 0, 0);
    t[5] = amd_buf_load_f32(r1.v, vr,  0, 0);
    t[6] = amd_buf_load_f32(r2.v, vl,  0, 0);
    t[7] = amd_buf_load_f32(r2.v, vcn, 0, 0);
    t[8] = amd_buf_load_f32(r2.v, vr,  0, 0);
}

#define FMA9(acc, W, T)                 \
    acc = fmaf((W)[0], (T)[0], acc);    \
    acc = fmaf((W)[1], (T)[1], acc);    \
    acc = fmaf((W)[2], (T)[2], acc);    \
    acc = fmaf((W)[3], (T)[3], acc);    \
    acc = fmaf((W)[4], (T)[4], acc);    \
    acc = fmaf((W)[5], (T)[5], acc);    \
    acc = fmaf((W)[6], (T)[6], acc);    \
    acc = fmaf((W)[7], (T)[7], acc);    \
    acc = fmaf((W)[8], (T)[8], acc);

__global__ __launch_bounds__(64, 4)
void TCA_49177375539279_kernel(const float* __restrict__ x,
                               const float* __restrict__ last,
                               const float* __restrict__ wq,
                               const float* __restrict__ wk,
                               const float* __restrict__ wv,
                               const float* __restrict__ wp,
                               float* __restrict__ out)
{
    // XCD swizzle: wg -> XCD is ~round-robin on flat id; give each XCD a
    // contiguous chunk of (z, y) work so y-adjacent rows share that XCD's L2.
    const int f  = (int)blockIdx.x;               // 0..16383
    const int w  = ((f & 7) << 11) | (f >> 3);    // contiguous 2048-chunk per XCD
    const int bx = w & 1;                         // x half (0..1)
    const int py = (w >> 1) & 127;                // row 0..127  (wave-uniform)
    const int z  = w >> 8;                        // 0..63
    const int bi = z >> 3;                        // batch
    const int hd = z & 7;                         // head
    const int px = (bx << 6) + (int)threadIdx.x;  // column 0..127

    const int    ch0     = hd << 3;               // first of 8 input channels
    const size_t base_in = (size_t)(bi * 64 + ch0) * CS;
    const float* xb = x    + base_in;
    const float* lb = last + base_in;

    // Fixed row-relative byte voffsets (reused by all 720 loads).
    const int vcn = px << 2;
    const int vl  = (px == 0) ? (int)0x80000000 : (vcn - 4);  // sentinel: OOB->0
    const int vr  = vcn + 4;                                  // px==127 -> OOB->0

    const unsigned nr_t = (py >= 1)   ? 512u : 0u;  // top row validity
    const unsigned nr_b = (py <= 126) ? 512u : 0u;  // bottom row validity
    const int row_off   = (py - 1) * 512;           // byte offset of row py-1

    // ---------------- pass 1: q = conv3x3x3(x, wq) ----------------
    float q[4][BD] = {};
#pragma unroll
    for (int ic = 0; ic < 8; ++ic) {
        const int c = ic >> 1;
        const float* wqi = wq + hd * 216 + ic * 27;
#pragma unroll
        for (int d = 0; d < BD; ++d) {
            float t[9];
            load9((const char*)(xb + (size_t)(ic * BD + d) * HWn) + row_off,
                  nr_t, nr_b, vl, vcn, vr, t);
#pragma unroll
            for (int dz = 0; dz < 3; ++dz) {
                const int i = d + 1 - dz;            // output depth fed by plane d
                if (i >= 0 && i < BD) {
                    const float* wz = wqi + dz * 9;
                    float a = q[c][i];
                    FMA9(a, wz, t);
                    q[c][i] = a;
                }
            }
        }
    }

    // ---------------- pass 2: k,v = conv3x3x3(last, wk/wv) ----------------
    float k[4][BD] = {}, v[4][BD] = {};
#pragma unroll
    for (int ic = 0; ic < 8; ++ic) {
        const int c = ic >> 1;
        const float* wki = wk + hd * 216 + ic * 27;
        const float* wvi = wv + hd * 216 + ic * 27;
#pragma unroll
        for (int d = 0; d < BD; ++d) {
            float t[9];
            load9((const char*)(lb + (size_t)(ic * BD + d) * HWn) + row_off,
                  nr_t, nr_b, vl, vcn, vr, t);
#pragma unroll
            for (int dz = 0; dz < 3; ++dz) {
                const int i = d + 1 - dz;
                if (i >= 0 && i < BD) {
                    const float* wzk = wki + dz * 9;
                    const float* wzv = wvi + dz * 9;
                    float a = k[c][i];
                    FMA9(a, wzk, t);
                    k[c][i] = a;
                    float b = v[c][i];
                    FMA9(b, wzv, t);
                    v[c][i] = b;
                }
            }
        }
    }

    // ---------------- attention: softmax_j( SCALE * q_i . k_j ) ----------------
    const float SCALE = 0.35355339059327373f;   // 8^-0.5
    float p[BD][BD];
#pragma unroll
    for (int i = 0; i < BD; ++i) {
        float s[BD];
        float m = -3.0e38f;
#pragma unroll
        for (int j = 0; j < BD; ++j) {
            float t = q[0][i] * k[0][j];
            t = fmaf(q[1][i], k[1][j], t);
            t = fmaf(q[2][i], k[2][j], t);
            t = fmaf(q[3][i], k[3][j], t);
            t *= SCALE;
            s[j] = t;
            m = fmaxf(m, t);
        }
        float sum = 0.f;
#pragma unroll
        for (int j = 0; j < BD; ++j) { float e = __expf(s[j] - m); p[i][j] = e; sum += e; }
        const float r = 1.0f / sum;
#pragma unroll
        for (int j = 0; j < BD; ++j) p[i][j] *= r;
    }

    // ---------------- out = attn @ v -> 1x1 grouped proj -> store ----------------
    SRD ro;
    ro.s.base = out + base_in;
    ro.s.nr   = (unsigned)(41943040u - (unsigned)base_in) * 4u;  // bytes left
    ro.s.cfg  = CFGW;
    const int sob = (py * WD) << 2;   // scalar byte offset of this row
#pragma unroll
    for (int c = 0; c < 4; ++c) {
        const float w0 = wp[ch0 + 2 * c];
        const float w1 = wp[ch0 + 2 * c + 1];
#pragma unroll
        for (int i = 0; i < BD; ++i) {
            float o = p[i][0] * v[c][0];
            o = fmaf(p[i][1], v[c][1], o);
            o = fmaf(p[i][2], v[c][2], o);
            o = fmaf(p[i][3], v[c][3], o);
            o = fmaf(p[i][4], v[c][4], o);
            amd_buf_store_f32(w0 * o, ro.v, vcn,
                              sob + (((2 * c)     * CS + i * HWn) << 2), 0);
            amd_buf_store_f32(w1 * o, ro.v, vcn,
                              sob + (((2 * c + 1) * CS + i * HWn) << 2), 0);
        }
    }
}

extern "C" void kernel_launch(void* const* d_in, const int* in_sizes, int n_in,
                              void* d_out, int out_size, void* d_ws, size_t ws_size,
                              hipStream_t stream)
{
    const float* x    = (const float*)d_in[0];
    const float* last = (const float*)d_in[1];
    const float* wq   = (const float*)d_in[2];
    const float* wk   = (const float*)d_in[3];
    const float* wv   = (const float*)d_in[4];
    const float* wp   = (const float*)d_in[5];
    float* out = (float*)d_out;

    dim3 grid(16384);   // 2 x-halves * 128 rows * 64 (batch*head)
    dim3 block(64);     // one wave: py is wave-uniform -> scalar SRDs
    hipLaunchKernelGGL(TCA_49177375539279_kernel, grid, block, 0, stream,
                       x, last, wq, wk, wv, wp, out);
}